// Round 2
// baseline (1255.335 us; speedup 1.0000x reference)
//
#include <hip/hip_runtime.h>
#include <math.h>

#define N_TOK 32768
#define DDIM  512
#define KCODE 1024
#define DECAYF 0.99f
#define EPSV 1e-5f
#define CCOST 0.25f
#define MARGIN 5e-3f

#define BM 64
#define BN 128
#define BD 32
#define XST (BM + 4)   // 68 floats: rows stay 16B-aligned
#define WST (BN + 4)   // 132 floats

// ---------------- codebook row norms (fp64 accurate, stored f32) ----------------
__global__ __launch_bounds__(64) void wnorm_kernel(const float* __restrict__ w,
                                                   float* __restrict__ wn) {
  int k = blockIdx.x;
  int lane = threadIdx.x;
  const float4* row = (const float4*)(w + (size_t)k * DDIM);
  float4 v0 = row[lane];
  float4 v1 = row[lane + 64];
  double s = (double)v0.x*(double)v0.x + (double)v0.y*(double)v0.y
           + (double)v0.z*(double)v0.z + (double)v0.w*(double)v0.w
           + (double)v1.x*(double)v1.x + (double)v1.y*(double)v1.y
           + (double)v1.z*(double)v1.z + (double)v1.w*(double)v1.w;
  for (int o = 32; o > 0; o >>= 1) s += __shfl_down(s, o, 64);
  if (lane == 0) wn[k] = (float)s;
}

// ---------------- fp32 distance + argmin (top-2, margin flag) ----------------
__global__ __launch_bounds__(256) void dist_kernel(
    const float* __restrict__ x, const float* __restrict__ w,
    const float* __restrict__ wnorm, const int* __restrict__ mask,
    int* __restrict__ idx_i, int* __restrict__ flagList, int* __restrict__ flagcnt)
{
  __shared__ float sX[BD * XST];
  __shared__ float sW[BD * WST];
  __shared__ float rm1[64][16];
  __shared__ float rm2[64][16];
  __shared__ int   ri1[64][16];

  const int tid = threadIdx.x;
  const int row0 = blockIdx.x * BM;
  const int tm = tid & 15, tn = tid >> 4;   // 16 x 16 thread grid
  const int cg = tid & 7,  rr = tid >> 3;   // staging decomposition

  float m1[4], m2[4]; int i1[4];
  #pragma unroll
  for (int t = 0; t < 4; t++) { m1[t] = 3.4e38f; m2[t] = 3.4e38f; i1[t] = 0x7fffffff; }

  for (int c = 0; c < KCODE / BN; c++) {
    float acc[4][8];
    #pragma unroll
    for (int t = 0; t < 4; t++)
      #pragma unroll
      for (int j = 0; j < 8; j++) acc[t][j] = 0.f;

    for (int ds = 0; ds < DDIM / BD; ds++) {
      #pragma unroll
      for (int it = 0; it < 2; it++) {
        int r = rr + 32 * it;
        float4 v = *(const float4*)(x + (size_t)(row0 + r) * DDIM + ds * BD + cg * 4);
        sX[(cg*4 + 0) * XST + r] = v.x;
        sX[(cg*4 + 1) * XST + r] = v.y;
        sX[(cg*4 + 2) * XST + r] = v.z;
        sX[(cg*4 + 3) * XST + r] = v.w;
      }
      #pragma unroll
      for (int it = 0; it < 4; it++) {
        int r = rr + 32 * it;
        float4 v = *(const float4*)(w + (size_t)(c * BN + r) * DDIM + ds * BD + cg * 4);
        sW[(cg*4 + 0) * WST + r] = v.x;
        sW[(cg*4 + 1) * WST + r] = v.y;
        sW[(cg*4 + 2) * WST + r] = v.z;
        sW[(cg*4 + 3) * WST + r] = v.w;
      }
      __syncthreads();
      #pragma unroll
      for (int d = 0; d < BD; d++) {
        float4 av = *(const float4*)(sX + d * XST + 4 * tm);
        float4 b0 = *(const float4*)(sW + d * WST + 8 * tn);
        float4 b1 = *(const float4*)(sW + d * WST + 8 * tn + 4);
        float a[4] = {av.x, av.y, av.z, av.w};
        float b[8] = {b0.x, b0.y, b0.z, b0.w, b1.x, b1.y, b1.z, b1.w};
        #pragma unroll
        for (int t = 0; t < 4; t++)
          #pragma unroll
          for (int j = 0; j < 8; j++)
            acc[t][j] = fmaf(a[t], b[j], acc[t][j]);
      }
      __syncthreads();
    }
    int k0 = c * BN + 8 * tn;
    float wnv[8];
    #pragma unroll
    for (int j = 0; j < 8; j++) wnv[j] = wnorm[k0 + j];
    #pragma unroll
    for (int j = 0; j < 8; j++) {
      int kk = k0 + j;
      if (kk == 0) continue;  // non-pad tokens may not pick code 0
      #pragma unroll
      for (int t = 0; t < 4; t++) {
        float dist = fmaf(-2.f, acc[t][j], wnv[j]);
        if (dist < m1[t]) { m2[t] = m1[t]; m1[t] = dist; i1[t] = kk; }
        else if (dist < m2[t]) m2[t] = dist;
      }
    }
  }

  #pragma unroll
  for (int t = 0; t < 4; t++) {
    rm1[4*tm + t][tn] = m1[t];
    rm2[4*tm + t][tn] = m2[t];
    ri1[4*tm + t][tn] = i1[t];
  }
  __syncthreads();
  if (tid < 64) {
    float bm1 = 3.4e38f, bm2 = 3.4e38f; int bi = 0x7fffffff;
    for (int cc = 0; cc < 16; cc++) {
      float v = rm1[tid][cc]; float v2 = rm2[tid][cc]; int ii = ri1[tid][cc];
      if (v < bm1 || (v == bm1 && ii < bi)) { bm2 = fminf(bm2, bm1); bm1 = v; bi = ii; }
      else bm2 = fminf(bm2, v);
      bm2 = fminf(bm2, v2);
    }
    int token = row0 + tid;
    int pad = mask[token];
    idx_i[token] = pad ? 0 : bi;
    if (!pad && (bm2 - bm1) < MARGIN) {
      int p = atomicAdd(flagcnt, 1);
      flagList[p] = token;
    }
  }
}

// ---------------- numpy-f32-emulating re-check for near-tie tokens ----------------
// Emulates: dist32 = fl32( fl32(A32 + B32[k]) - 2.f*fl32(dot64) ), argmin first-index.
// A32/B32/M32 from fp64 sums rounded to f32; integer-ulp common shifts in A32
// preserve the f32 rounding-grid tie structure exactly.
__global__ __launch_bounds__(256) void refine_kernel(
    const float* __restrict__ x, const float* __restrict__ w,
    const float* __restrict__ wn32,
    const int* __restrict__ flagList, const int* __restrict__ flagcnt,
    int* __restrict__ idx_i)
{
  __shared__ double xd[DDIM];
  __shared__ double redbuf[4];
  __shared__ float A32sh;
  __shared__ float bv_s[256];
  __shared__ int   bi_s[256];
  int tid = threadIdx.x;
  int lane = tid & 63, wid = tid >> 6;
  int nf = *flagcnt;
  for (int fi = blockIdx.x; fi < nf; fi += gridDim.x) {
    int token = flagList[fi];
    double part = 0.0;
    for (int e = tid; e < DDIM; e += 256) {
      double v = (double)x[(size_t)token * DDIM + e];
      xd[e] = v;
      part += v * v;
    }
    for (int o = 32; o > 0; o >>= 1) part += __shfl_down(part, o, 64);
    if (lane == 0) redbuf[wid] = part;
    __syncthreads();
    if (tid == 0) {
      double a64 = redbuf[0] + redbuf[1] + redbuf[2] + redbuf[3];
      A32sh = (float)a64;
    }
    __syncthreads();
    float A32 = A32sh;
    float bv = 3.4e38f; int bi = 0x7fffffff;
    for (int k = tid; k < KCODE; k += 256) {
      if (k == 0) continue;
      const float4* wr = (const float4*)(w + (size_t)k * DDIM);
      double dot = 0.0;
      #pragma unroll 4
      for (int dq = 0; dq < DDIM / 4; dq++) {
        float4 wv = wr[dq];
        dot += xd[dq*4+0]*(double)wv.x + xd[dq*4+1]*(double)wv.y
             + xd[dq*4+2]*(double)wv.z + xd[dq*4+3]*(double)wv.w;
      }
      float M = (float)dot;
      float AB = A32 + wn32[k];
      float dist = AB - 2.0f * M;   // 2*M exact in f32; fma contraction harmless
      if (dist < bv) { bv = dist; bi = k; }   // k ascending: strict < == first index
    }
    bv_s[tid] = bv; bi_s[tid] = bi;
    __syncthreads();
    for (int st = 128; st > 0; st >>= 1) {
      if (tid < st) {
        if (bv_s[tid+st] < bv_s[tid] ||
            (bv_s[tid+st] == bv_s[tid] && bi_s[tid+st] < bi_s[tid])) {
          bv_s[tid] = bv_s[tid+st]; bi_s[tid] = bi_s[tid+st];
        }
      }
      __syncthreads();
    }
    if (tid == 0) idx_i[token] = bi_s[0];
    __syncthreads();
  }
}

// ---------------- gather + loss partials + counts + dw scatter ----------------
__global__ __launch_bounds__(128) void gather_kernel(
    const float* __restrict__ x, const float* __restrict__ w,
    const int* __restrict__ idx_i,
    float* __restrict__ out_q, float* __restrict__ out_idx,
    float* __restrict__ counts, float* __restrict__ dw, float* __restrict__ losssum)
{
  __shared__ float sred[2];
  int token = blockIdx.x; int tid = threadIdx.x;
  int idx = idx_i[token];
  float4 xv = *(const float4*)(x + (size_t)token * DDIM + tid * 4);
  float4 wv = *(const float4*)(w + (size_t)idx * DDIM + tid * 4);
  *(float4*)(out_q + (size_t)token * DDIM + tid * 4) = wv;
  float dx = wv.x - xv.x, dy = wv.y - xv.y, dz = wv.z - xv.z, dww = wv.w - xv.w;
  float s = dx*dx + dy*dy + dz*dz + dww*dww;
  for (int o = 32; o > 0; o >>= 1) s += __shfl_down(s, o, 64);
  int lane = tid & 63, wid = tid >> 6;
  if (lane == 0) sred[wid] = s;
  __syncthreads();
  if (tid == 0) {
    atomicAdd(losssum, sred[0] + sred[1]);
    atomicAdd(counts + idx, 1.0f);
    out_idx[token] = (float)idx;
  }
  float* dwr = dw + (size_t)idx * DDIM + tid * 4;
  atomicAdd(dwr + 0, xv.x);
  atomicAdd(dwr + 1, xv.y);
  atomicAdd(dwr + 2, xv.z);
  atomicAdd(dwr + 3, xv.w);
}

// ---------------- cs / loss / perplexity ----------------
__global__ __launch_bounds__(1024) void stats_kernel(
    const float* __restrict__ counts, const float* __restrict__ ema_cs,
    const float* __restrict__ losssum,
    float* __restrict__ out_loss, float* __restrict__ out_perp,
    float* __restrict__ out_cs)
{
  __shared__ float sbuf[17];
  int k = threadIdx.x;
  float cnt = counts[k];
  float csr = ema_cs[k] * DECAYF + (1.f - DECAYF) * cnt;
  float v = csr;
  for (int o = 32; o > 0; o >>= 1) v += __shfl_down(v, o, 64);
  int lane = k & 63, wid = k >> 6;
  if (lane == 0) sbuf[wid] = v;
  __syncthreads();
  if (k == 0) { float n = 0.f; for (int i = 0; i < 16; i++) n += sbuf[i]; sbuf[16] = n; }
  __syncthreads();
  float n = sbuf[16];
  out_cs[k] = (csr + EPSV) / (n + (float)KCODE * EPSV) * n;
  __syncthreads();
  float p = cnt / (float)N_TOK;
  v = p * logf(p + 1e-10f);
  for (int o = 32; o > 0; o >>= 1) v += __shfl_down(v, o, 64);
  if (lane == 0) sbuf[wid] = v;
  __syncthreads();
  if (k == 0) {
    float s = 0.f; for (int i = 0; i < 16; i++) s += sbuf[i];
    out_perp[0] = expf(-s);
    float nonpad = (float)N_TOK - counts[0];  // counts[0] == #pad tokens
    out_loss[0] = CCOST * losssum[0] / (nonpad * (float)DDIM);
  }
}

// ---------------- EMA update + new codebook ----------------
__global__ __launch_bounds__(256) void ema_kernel(
    const float* __restrict__ ema_w, const float* __restrict__ dw,
    const float* __restrict__ cs,
    float* __restrict__ out_ema, float* __restrict__ out_cb)
{
  int i = blockIdx.x * 256 + threadIdx.x;  // float4 index
  int e = i * 4;
  int k = e >> 9;                          // / DDIM
  float4 ew = *(const float4*)(ema_w + e);
  float4 dv = *(const float4*)(dw + e);
  float4 ne;
  ne.x = ew.x * DECAYF + (1.f - DECAYF) * dv.x;
  ne.y = ew.y * DECAYF + (1.f - DECAYF) * dv.y;
  ne.z = ew.z * DECAYF + (1.f - DECAYF) * dv.z;
  ne.w = ew.w * DECAYF + (1.f - DECAYF) * dv.w;
  *(float4*)(out_ema + e) = ne;
  float4 cb;
  if (k == 0) { cb.x = 0.f; cb.y = 0.f; cb.z = 0.f; cb.w = 0.f; }
  else {
    float csk = cs[k];
    cb.x = ne.x / csk; cb.y = ne.y / csk; cb.z = ne.z / csk; cb.w = ne.w / csk;
  }
  *(float4*)(out_cb + e) = cb;
}

extern "C" void kernel_launch(void* const* d_in, const int* in_sizes, int n_in,
                              void* d_out, int out_size, void* d_ws, size_t ws_size,
                              hipStream_t stream) {
  const float* x      = (const float*)d_in[0];
  const int*   mask   = (const int*)d_in[1];
  const float* w      = (const float*)d_in[2];
  const float* ema_cs = (const float*)d_in[3];
  const float* ema_w  = (const float*)d_in[4];
  float* out = (float*)d_out;

  float* out_q    = out;                  // 16777216  quantized_st
  float* out_idx  = out + 16777216;       // 32768     idx (as float)
  float* out_loss = out + 16809984;       // 1
  float* out_perp = out + 16809985;       // 1
  float* out_cs   = out + 16809986;       // 1024
  float* out_ema  = out + 16811010;       // 524288
  float* out_cb   = out + 17335298;       // 524288

  char* ws = (char*)d_ws;
  float* counts   = (float*)(ws + 0);                    // 4 KB
  float* dw       = (float*)(ws + 4096);                 // 2 MB
  float* losssum  = (float*)(ws + 4096 + 2097152);       // scalar
  int*   flagcnt  = (int*)  (ws + 4096 + 2097152 + 4);
  // zero region: [0, 2101312)
  float* wnorm    = (float*)(ws + 2101312);              // 4 KB
  int*   idx_i    = (int*)  (ws + 2101312 + 4096);       // 128 KB
  int*   flagList = (int*)  (ws + 2101312 + 4096 + 131072); // 128 KB

  hipMemsetAsync(d_ws, 0, 2101312, stream);
  wnorm_kernel<<<KCODE, 64, 0, stream>>>(w, wnorm);
  dist_kernel<<<N_TOK / BM, 256, 0, stream>>>(x, w, wnorm, mask, idx_i, flagList, flagcnt);
  refine_kernel<<<1024, 256, 0, stream>>>(x, w, wnorm, flagList, flagcnt, idx_i);
  gather_kernel<<<N_TOK, 128, 0, stream>>>(x, w, idx_i, out_q, out_idx, counts, dw, losssum);
  stats_kernel<<<1, 1024, 0, stream>>>(counts, ema_cs, losssum, out_loss, out_perp, out_cs);
  ema_kernel<<<KCODE * DDIM / 4 / 256, 256, 0, stream>>>(ema_w, dw, out_cs, out_ema, out_cb);
}

// Round 3
// 995.441 us; speedup vs baseline: 1.2611x; 1.2611x over previous
//
#include <hip/hip_runtime.h>
#include <math.h>

#define N_TOK 32768
#define DDIM  512
#define KCODE 1024
#define DECAYF 0.99f
#define EPSV 1e-5f
#define CCOST 0.25f
#define MARGIN 5e-3f

#define BM 64
#define BN 128
#define BD 32
#define KHALF 512
#define XST (BM + 4)   // 68: rows 16B-aligned
#define WST (BN + 4)   // 132

// ---------------- codebook row norms (fp64 accurate, stored f32) ----------------
__global__ __launch_bounds__(64) void wnorm_kernel(const float* __restrict__ w,
                                                   float* __restrict__ wn) {
  int k = blockIdx.x;
  int lane = threadIdx.x;
  const float4* row = (const float4*)(w + (size_t)k * DDIM);
  float4 v0 = row[lane];
  float4 v1 = row[lane + 64];
  double s = (double)v0.x*(double)v0.x + (double)v0.y*(double)v0.y
           + (double)v0.z*(double)v0.z + (double)v0.w*(double)v0.w
           + (double)v1.x*(double)v1.x + (double)v1.y*(double)v1.y
           + (double)v1.z*(double)v1.z + (double)v1.w*(double)v1.w;
  for (int o = 32; o > 0; o >>= 1) s += __shfl_down(s, o, 64);
  if (lane == 0) wn[k] = (float)s;
}

// ---------------- fp32 distance + per-half top-2 ----------------
// grid = (N_TOK/BM) * 2; block handles 64 tokens x 512 codes (one K-half).
// LDS staging rotation-swizzled: token/code r stored in row d at col (r + 4*(d>>2)) & mask
// -> staging writes 2-way (free), reads stay b128-aligned.
__global__ __launch_bounds__(256) void dist_kernel(
    const float* __restrict__ x, const float* __restrict__ w,
    const float* __restrict__ wnorm,
    float* __restrict__ hm1, float* __restrict__ hm2, int* __restrict__ hi1)
{
  __shared__ float smem[BD * XST + BD * WST];   // 25.6 KB
  float* sX = smem;
  float* sW = smem + BD * XST;
  // reduction arrays overlap sW after the main loop
  float* rm1 = sW;
  float* rm2 = sW + 1024;
  int*   ri1 = (int*)(sW + 2048);

  const int tid = threadIdx.x;
  const int tb = blockIdx.x >> 1;
  const int kh = blockIdx.x & 1;
  const int row0 = tb * BM;
  const int tm = tid & 15, tn = tid >> 4;   // 16x16 thread grid
  const int cg = tid & 7,  rr = tid >> 3;   // staging decomposition

  // precomputed swizzled columns per sh = d>>2 (8 values)
  int xcol[8], wc0[8], wc1[8];
  #pragma unroll
  for (int s = 0; s < 8; s++) {
    xcol[s] = 4 * ((tm + s) & 15);
    wc0[s] = (8 * tn + 4 * s) & 127;
    wc1[s] = (8 * tn + 4 + 4 * s) & 127;
  }

  float m1[4], m2[4]; int i1[4];
  #pragma unroll
  for (int t = 0; t < 4; t++) { m1[t] = 3.4e38f; m2[t] = 3.4e38f; i1[t] = 0x7fffffff; }

  for (int c = 0; c < KHALF / BN; c++) {
    float acc[4][8];
    #pragma unroll
    for (int t = 0; t < 4; t++)
      #pragma unroll
      for (int j = 0; j < 8; j++) acc[t][j] = 0.f;

    for (int ds = 0; ds < DDIM / BD; ds++) {
      #pragma unroll
      for (int it = 0; it < 2; it++) {
        int r = rr + 32 * it;
        float4 v = *(const float4*)(x + (size_t)(row0 + r) * DDIM + ds * BD + cg * 4);
        int col = (r + 4 * cg) & 63;
        sX[(cg*4 + 0) * XST + col] = v.x;
        sX[(cg*4 + 1) * XST + col] = v.y;
        sX[(cg*4 + 2) * XST + col] = v.z;
        sX[(cg*4 + 3) * XST + col] = v.w;
      }
      #pragma unroll
      for (int it = 0; it < 4; it++) {
        int r = rr + 32 * it;
        float4 v = *(const float4*)(w + (size_t)(kh * KHALF + c * BN + r) * DDIM + ds * BD + cg * 4);
        int col = (r + 4 * cg) & 127;
        sW[(cg*4 + 0) * WST + col] = v.x;
        sW[(cg*4 + 1) * WST + col] = v.y;
        sW[(cg*4 + 2) * WST + col] = v.z;
        sW[(cg*4 + 3) * WST + col] = v.w;
      }
      __syncthreads();
      #pragma unroll
      for (int d = 0; d < BD; d++) {
        const int sh = d >> 2;
        float4 av = *(const float4*)(sX + d * XST + xcol[sh]);
        float4 b0 = *(const float4*)(sW + d * WST + wc0[sh]);
        float4 b1 = *(const float4*)(sW + d * WST + wc1[sh]);
        float a[4] = {av.x, av.y, av.z, av.w};
        float b[8] = {b0.x, b0.y, b0.z, b0.w, b1.x, b1.y, b1.z, b1.w};
        #pragma unroll
        for (int t = 0; t < 4; t++)
          #pragma unroll
          for (int j = 0; j < 8; j++)
            acc[t][j] = fmaf(a[t], b[j], acc[t][j]);
      }
      __syncthreads();
    }
    int k0 = kh * KHALF + c * BN + 8 * tn;
    float wnv[8];
    #pragma unroll
    for (int j = 0; j < 8; j++) wnv[j] = wnorm[k0 + j];
    #pragma unroll
    for (int j = 0; j < 8; j++) {
      int kk = k0 + j;
      if (kk == 0) continue;  // non-pad tokens may not pick code 0
      #pragma unroll
      for (int t = 0; t < 4; t++) {
        float dist = fmaf(-2.f, acc[t][j], wnv[j]);
        if (dist < m1[t]) { m2[t] = m1[t]; m1[t] = dist; i1[t] = kk; }
        else if (dist < m2[t]) m2[t] = dist;
      }
    }
  }

  // all threads past final inner barrier; sW no longer read -> reuse for reduction
  #pragma unroll
  for (int t = 0; t < 4; t++) {
    rm1[(4*tm + t) * 16 + tn] = m1[t];
    rm2[(4*tm + t) * 16 + tn] = m2[t];
    ri1[(4*tm + t) * 16 + tn] = i1[t];
  }
  __syncthreads();
  if (tid < 64) {
    float bm1 = 3.4e38f, bm2 = 3.4e38f; int bi = 0x7fffffff;
    for (int cc = 0; cc < 16; cc++) {
      float v = rm1[tid * 16 + cc]; float v2 = rm2[tid * 16 + cc]; int ii = ri1[tid * 16 + cc];
      if (v < bm1 || (v == bm1 && ii < bi)) { bm2 = fminf(bm2, bm1); bm1 = v; bi = ii; }
      else bm2 = fminf(bm2, v);
      bm2 = fminf(bm2, v2);
    }
    int token = row0 + tid;
    hm1[kh * N_TOK + token] = bm1;
    hm2[kh * N_TOK + token] = bm2;
    hi1[kh * N_TOK + token] = bi;
  }
}

// ---------------- merge halves, pad mask, margin flag ----------------
__global__ __launch_bounds__(256) void combine_kernel(
    const float* __restrict__ hm1, const float* __restrict__ hm2,
    const int* __restrict__ hi1, const int* __restrict__ mask,
    int* __restrict__ idx_i, int* __restrict__ flagList, int* __restrict__ flagcnt)
{
  int t = blockIdx.x * 256 + threadIdx.x;
  float a1 = hm1[t], a2 = hm2[t]; int ia = hi1[t];
  float b1 = hm1[N_TOK + t], b2 = hm2[N_TOK + t]; int ib = hi1[N_TOK + t];
  float best, second; int bi;
  if (b1 < a1) { best = b1; bi = ib; second = fminf(b2, a1); }
  else         { best = a1; bi = ia; second = fminf(a2, b1); }  // tie -> lower-k half; margin 0 -> refine
  int pad = mask[t];
  idx_i[t] = pad ? 0 : bi;
  if (!pad && (second - best) < MARGIN) {
    int p = atomicAdd(flagcnt, 1);
    flagList[p] = t;
  }
}

// ---------------- numpy-f32-emulating re-check for near-tie tokens ----------------
__global__ __launch_bounds__(256) void refine_kernel(
    const float* __restrict__ x, const float* __restrict__ w,
    const float* __restrict__ wn32,
    const int* __restrict__ flagList, const int* __restrict__ flagcnt,
    int* __restrict__ idx_i)
{
  __shared__ double xd[DDIM];
  __shared__ double redbuf[4];
  __shared__ float A32sh;
  __shared__ float bv_s[256];
  __shared__ int   bi_s[256];
  int tid = threadIdx.x;
  int lane = tid & 63, wid = tid >> 6;
  int nf = *flagcnt;
  for (int fi = blockIdx.x; fi < nf; fi += gridDim.x) {
    int token = flagList[fi];
    double part = 0.0;
    for (int e = tid; e < DDIM; e += 256) {
      double v = (double)x[(size_t)token * DDIM + e];
      xd[e] = v;
      part += v * v;
    }
    for (int o = 32; o > 0; o >>= 1) part += __shfl_down(part, o, 64);
    if (lane == 0) redbuf[wid] = part;
    __syncthreads();
    if (tid == 0) {
      double a64 = redbuf[0] + redbuf[1] + redbuf[2] + redbuf[3];
      A32sh = (float)a64;
    }
    __syncthreads();
    float A32 = A32sh;
    float bv = 3.4e38f; int bi = 0x7fffffff;
    for (int k = tid; k < KCODE; k += 256) {
      if (k == 0) continue;
      const float4* wr = (const float4*)(w + (size_t)k * DDIM);
      double dot = 0.0;
      #pragma unroll 4
      for (int dq = 0; dq < DDIM / 4; dq++) {
        float4 wv = wr[dq];
        dot += xd[dq*4+0]*(double)wv.x + xd[dq*4+1]*(double)wv.y
             + xd[dq*4+2]*(double)wv.z + xd[dq*4+3]*(double)wv.w;
      }
      float M = (float)dot;
      float AB = A32 + wn32[k];
      float dist = AB - 2.0f * M;
      if (dist < bv) { bv = dist; bi = k; }
    }
    bv_s[tid] = bv; bi_s[tid] = bi;
    __syncthreads();
    for (int st = 128; st > 0; st >>= 1) {
      if (tid < st) {
        if (bv_s[tid+st] < bv_s[tid] ||
            (bv_s[tid+st] == bv_s[tid] && bi_s[tid+st] < bi_s[tid])) {
          bv_s[tid] = bv_s[tid+st]; bi_s[tid] = bi_s[tid+st];
        }
      }
      __syncthreads();
    }
    if (tid == 0) idx_i[token] = bi_s[0];
    __syncthreads();
  }
}

// ---------------- histogram (post-refine) + out_idx ----------------
__global__ __launch_bounds__(256) void hist_kernel(
    const int* __restrict__ idx_i, int* __restrict__ counts_i,
    float* __restrict__ out_idx)
{
  int t = blockIdx.x * 256 + threadIdx.x;
  int id = idx_i[t];
  atomicAdd(&counts_i[id], 1);
  out_idx[t] = (float)id;
}

// ---------------- exclusive scan of counts (1 block, 1024 thr) ----------------
__global__ __launch_bounds__(1024) void scan_kernel(
    const int* __restrict__ counts_i, int* __restrict__ offsets, int* __restrict__ cursor)
{
  __shared__ int tmp[1024];
  int t = threadIdx.x;
  int c = counts_i[t];
  tmp[t] = c;
  __syncthreads();
  for (int off = 1; off < 1024; off <<= 1) {
    int v = (t >= off) ? tmp[t - off] : 0;
    __syncthreads();
    tmp[t] += v;
    __syncthreads();
  }
  int ex = tmp[t] - c;
  offsets[t] = ex;
  cursor[t] = ex;
}

// ---------------- scatter tokens into per-code buckets ----------------
__global__ __launch_bounds__(256) void scatter_kernel(
    const int* __restrict__ idx_i, int* __restrict__ cursor, int* __restrict__ bucket)
{
  int t = blockIdx.x * 256 + threadIdx.x;
  int id = idx_i[t];
  int p = atomicAdd(&cursor[id], 1);
  bucket[p] = t;
}

// ---------------- quantized output + loss (16 tokens/block) ----------------
__global__ __launch_bounds__(256) void quant_kernel(
    const float* __restrict__ x, const float* __restrict__ w,
    const int* __restrict__ idx_i,
    float* __restrict__ out_q, float* __restrict__ losssum)
{
  __shared__ float sred[4];
  int tid = threadIdx.x;
  int q = tid & 127, h = tid >> 7;
  float s = 0.f;
  #pragma unroll
  for (int i = 0; i < 8; i++) {
    int token = blockIdx.x * 16 + i * 2 + h;
    int idx = idx_i[token];
    float4 xv = *(const float4*)(x + (size_t)token * DDIM + q * 4);
    float4 wv = *(const float4*)(w + (size_t)idx * DDIM + q * 4);
    *(float4*)(out_q + (size_t)token * DDIM + q * 4) = wv;
    float dx = wv.x - xv.x, dy = wv.y - xv.y, dz = wv.z - xv.z, dww = wv.w - xv.w;
    s += dx*dx + dy*dy + dz*dz + dww*dww;
  }
  for (int o = 32; o > 0; o >>= 1) s += __shfl_down(s, o, 64);
  int lane = tid & 63, wid = tid >> 6;
  if (lane == 0) sred[wid] = s;
  __syncthreads();
  if (tid == 0) atomicAdd(losssum, sred[0] + sred[1] + sred[2] + sred[3]);
}

// ---------------- dw: per (code, slice) register accumulation, no atomics ----------------
__global__ __launch_bounds__(128) void dw_kernel(
    const float* __restrict__ x, const int* __restrict__ bucket,
    const int* __restrict__ offsets, const int* __restrict__ counts_i,
    float* __restrict__ dwpart, int S)
{
  int s = blockIdx.x;       // slice
  int code = blockIdx.y;
  int t = threadIdx.x;
  float4 acc = make_float4(0.f, 0.f, 0.f, 0.f);
  int base = offsets[code], cnt = counts_i[code];
  for (int j = s; j < cnt; j += S) {
    int token = bucket[base + j];
    float4 xv = *(const float4*)(x + (size_t)token * DDIM + t * 4);
    acc.x += xv.x; acc.y += xv.y; acc.z += xv.z; acc.w += xv.w;
  }
  *(float4*)(dwpart + ((size_t)s * KCODE + code) * DDIM + t * 4) = acc;
}

// ---------------- cs / loss / perplexity ----------------
__global__ __launch_bounds__(1024) void stats_kernel(
    const int* __restrict__ counts_i, const float* __restrict__ ema_cs,
    const float* __restrict__ losssum,
    float* __restrict__ out_loss, float* __restrict__ out_perp,
    float* __restrict__ out_cs)
{
  __shared__ float sbuf[17];
  int k = threadIdx.x;
  float cnt = (float)counts_i[k];
  float csr = ema_cs[k] * DECAYF + (1.f - DECAYF) * cnt;
  float v = csr;
  for (int o = 32; o > 0; o >>= 1) v += __shfl_down(v, o, 64);
  int lane = k & 63, wid = k >> 6;
  if (lane == 0) sbuf[wid] = v;
  __syncthreads();
  if (k == 0) { float n = 0.f; for (int i = 0; i < 16; i++) n += sbuf[i]; sbuf[16] = n; }
  __syncthreads();
  float n = sbuf[16];
  out_cs[k] = (csr + EPSV) / (n + (float)KCODE * EPSV) * n;
  __syncthreads();
  float p = cnt / (float)N_TOK;
  v = p * logf(p + 1e-10f);
  for (int o = 32; o > 0; o >>= 1) v += __shfl_down(v, o, 64);
  if (lane == 0) sbuf[wid] = v;
  __syncthreads();
  if (k == 0) {
    float s = 0.f; for (int i = 0; i < 16; i++) s += sbuf[i];
    out_perp[0] = expf(-s);
    float nonpad = (float)(N_TOK - counts_i[0]);  // counts[0] == #pad tokens
    out_loss[0] = CCOST * losssum[0] / (nonpad * (float)DDIM);
  }
}

// ---------------- EMA update + new codebook (sums S dw parts) ----------------
__global__ __launch_bounds__(256) void ema_kernel(
    const float* __restrict__ ema_w, const float* __restrict__ dwpart,
    const float* __restrict__ cs, int S,
    float* __restrict__ out_ema, float* __restrict__ out_cb)
{
  int i = blockIdx.x * 256 + threadIdx.x;  // float4 index
  int e = i * 4;
  int k = e >> 9;
  float4 dv = make_float4(0.f, 0.f, 0.f, 0.f);
  for (int s = 0; s < S; s++) {
    float4 p = *(const float4*)(dwpart + (size_t)s * KCODE * DDIM + e);
    dv.x += p.x; dv.y += p.y; dv.z += p.z; dv.w += p.w;
  }
  float4 ew = *(const float4*)(ema_w + e);
  float4 ne;
  ne.x = ew.x * DECAYF + (1.f - DECAYF) * dv.x;
  ne.y = ew.y * DECAYF + (1.f - DECAYF) * dv.y;
  ne.z = ew.z * DECAYF + (1.f - DECAYF) * dv.z;
  ne.w = ew.w * DECAYF + (1.f - DECAYF) * dv.w;
  *(float4*)(out_ema + e) = ne;
  float4 cb;
  if (k == 0) { cb.x = 0.f; cb.y = 0.f; cb.z = 0.f; cb.w = 0.f; }
  else {
    float csk = cs[k];
    cb.x = ne.x / csk; cb.y = ne.y / csk; cb.z = ne.z / csk; cb.w = ne.w / csk;
  }
  *(float4*)(out_cb + e) = cb;
}

extern "C" void kernel_launch(void* const* d_in, const int* in_sizes, int n_in,
                              void* d_out, int out_size, void* d_ws, size_t ws_size,
                              hipStream_t stream) {
  const float* x      = (const float*)d_in[0];
  const int*   mask   = (const int*)d_in[1];
  const float* w      = (const float*)d_in[2];
  const float* ema_cs = (const float*)d_in[3];
  const float* ema_w  = (const float*)d_in[4];
  float* out = (float*)d_out;

  float* out_q    = out;                  // 16777216  quantized_st
  float* out_idx  = out + 16777216;       // 32768     idx (as float)
  float* out_loss = out + 16809984;       // 1
  float* out_perp = out + 16809985;       // 1
  float* out_cs   = out + 16809986;       // 1024
  float* out_ema  = out + 16811010;       // 524288
  float* out_cb   = out + 17335298;       // 524288

  char* ws = (char*)d_ws;
  int*   counts_i = (int*)  (ws + 0);        // 4 KB   (zeroed)
  float* losssum  = (float*)(ws + 4096);     // 4 B    (zeroed)
  int*   flagcnt  = (int*)  (ws + 4100);     // 4 B    (zeroed)
  int*   offsets  = (int*)  (ws + 8192);     // 4 KB
  int*   cursor   = (int*)  (ws + 12288);    // 4 KB
  float* wnorm    = (float*)(ws + 16384);    // 4 KB
  int*   idx_i    = (int*)  (ws + 20480);    // 128 KB
  int*   bucket   = (int*)  (ws + 151552);   // 128 KB
  float* hm1      = (float*)(ws + 282624);   // 256 KB  (consumed by combine)
  float* hm2      = (float*)(ws + 544768);   // 256 KB
  int*   hi1      = (int*)  (ws + 806912);   // 256 KB
  int*   flagList = (int*)  (ws + 1069056);  // 128 KB  (consumed by refine)
  // dwpart overlaps hm1..flagList (all consumed before dw_kernel runs)
  float* dwpart   = (float*)(ws + 282624);

  // pick slice count S for dw by available workspace
  int S = 1;
  if (ws_size >= 282624ull + 8ull * 2097152ull) S = 8;
  else if (ws_size >= 282624ull + 4ull * 2097152ull) S = 4;
  else if (ws_size >= 282624ull + 2ull * 2097152ull) S = 2;

  hipMemsetAsync(ws, 0, 4104, stream);
  wnorm_kernel<<<KCODE, 64, 0, stream>>>(w, wnorm);
  dist_kernel<<<(N_TOK / BM) * 2, 256, 0, stream>>>(x, w, wnorm, hm1, hm2, hi1);
  combine_kernel<<<N_TOK / 256, 256, 0, stream>>>(hm1, hm2, hi1, mask, idx_i, flagList, flagcnt);
  refine_kernel<<<1024, 256, 0, stream>>>(x, w, wnorm, flagList, flagcnt, idx_i);
  hist_kernel<<<N_TOK / 256, 256, 0, stream>>>(idx_i, counts_i, out_idx);
  scan_kernel<<<1, 1024, 0, stream>>>(counts_i, offsets, cursor);
  scatter_kernel<<<N_TOK / 256, 256, 0, stream>>>(idx_i, cursor, bucket);
  quant_kernel<<<N_TOK / 16, 256, 0, stream>>>(x, w, idx_i, out_q, losssum);
  dw_kernel<<<dim3(S, KCODE), 128, 0, stream>>>(x, bucket, offsets, counts_i, dwpart, S);
  stats_kernel<<<1, 1024, 0, stream>>>(counts_i, ema_cs, losssum, out_loss, out_perp, out_cs);
  ema_kernel<<<KCODE * DDIM / 4 / 256, 256, 0, stream>>>(ema_w, dwpart, out_cs, S, out_ema, out_cb);
}

// Round 4
// 725.300 us; speedup vs baseline: 1.7308x; 1.3725x over previous
//
#include <hip/hip_runtime.h>
#include <math.h>

#define N_TOK 32768
#define DDIM  512
#define KCODE 1024
#define DECAYF 0.99f
#define EPSV 1e-5f
#define CCOST 0.25f
#define MARGIN 5e-3f

typedef float f32x4 __attribute__((ext_vector_type(4)));
typedef short short8v __attribute__((ext_vector_type(8)));

// ---- bf16 helpers (RTN-even, matches HW cvt) ----
__device__ __forceinline__ unsigned short f2bf(float f) {
  unsigned u = __float_as_uint(f);
  u += 0x7fffu + ((u >> 16) & 1u);
  return (unsigned short)(u >> 16);
}
__device__ __forceinline__ float bf2f(unsigned short h) {
  return __uint_as_float(((unsigned)h) << 16);
}

// ---- monotone float<->ordered-uint for argmin key packing ----
__device__ __forceinline__ unsigned ordf(float f) {
  unsigned u = __float_as_uint(f);
  return (u & 0x80000000u) ? ~u : (u | 0x80000000u);
}
__device__ __forceinline__ float ord2f(unsigned v) {
  unsigned u = (v & 0x80000000u) ? (v & 0x7fffffffu) : ~v;
  return __uint_as_float(u);
}
// merge sorted pairs (a1<=a2),(b1<=b2) -> two smallest in (a1,a2)
__device__ __forceinline__ void top2m(unsigned long long& a1, unsigned long long& a2,
                                      unsigned long long b1, unsigned long long b2) {
  unsigned long long m1 = a1 < b1 ? a1 : b1;
  unsigned long long hi = a1 < b1 ? b1 : a1;
  unsigned long long m2 = a2 < b2 ? a2 : b2;
  a2 = m2 < hi ? m2 : hi;
  a1 = m1;
}

// ---- async global->LDS, 16B/lane; lds_base must be wave-uniform ----
__device__ __forceinline__ void stage16(const void* g, char* lds_base, int lane) {
#if __has_builtin(__builtin_amdgcn_global_load_lds)
  __builtin_amdgcn_global_load_lds((const __attribute__((address_space(1))) void*)g,
                                   (__attribute__((address_space(3))) void*)lds_base,
                                   16, 0, 0);
#else
  *(float4*)(lds_base + lane * 16) = *(const float4*)g;
#endif
}

// ---------------- x -> bf16 hi/lo split ----------------
__global__ __launch_bounds__(256) void convert_x(const float* __restrict__ x,
    unsigned short* __restrict__ xhi, unsigned short* __restrict__ xlo) {
  size_t i = (size_t)blockIdx.x * 256 + threadIdx.x;  // float4 index
  float4 v = *(const float4*)(x + i * 4);
  ushort4 h, l;
  h.x = f2bf(v.x); l.x = f2bf(v.x - bf2f(h.x));
  h.y = f2bf(v.y); l.y = f2bf(v.y - bf2f(h.y));
  h.z = f2bf(v.z); l.z = f2bf(v.z - bf2f(h.z));
  h.w = f2bf(v.w); l.w = f2bf(v.w - bf2f(h.w));
  *(ushort4*)(xhi + i * 4) = h;
  *(ushort4*)(xlo + i * 4) = l;
}

// ---------------- w -> bf16 hi/lo split + fp64 row norm ----------------
__global__ __launch_bounds__(64) void convert_w(const float* __restrict__ w,
    unsigned short* __restrict__ whi, unsigned short* __restrict__ wlo,
    float* __restrict__ wn) {
  int k = blockIdx.x;
  int lane = threadIdx.x;
  double s = 0.0;
  #pragma unroll
  for (int it = 0; it < 2; it++) {
    size_t off = (size_t)k * DDIM + (lane + 64 * it) * 4;
    float4 v = *(const float4*)(w + off);
    s += (double)v.x*(double)v.x + (double)v.y*(double)v.y
       + (double)v.z*(double)v.z + (double)v.w*(double)v.w;
    ushort4 h, l;
    h.x = f2bf(v.x); l.x = f2bf(v.x - bf2f(h.x));
    h.y = f2bf(v.y); l.y = f2bf(v.y - bf2f(h.y));
    h.z = f2bf(v.z); l.z = f2bf(v.z - bf2f(h.z));
    h.w = f2bf(v.w); l.w = f2bf(v.w - bf2f(h.w));
    *(ushort4*)(whi + off) = h;
    *(ushort4*)(wlo + off) = l;
  }
  for (int o = 32; o > 0; o >>= 1) s += __shfl_down(s, o, 64);
  if (lane == 0) wn[k] = (float)s;
}

// ---------------- MFMA distance + top-2 argmin ----------------
// grid = (N_TOK/128) * 8; block: 128 tokens x 128 codes, K'=1536 (3 bf16 segments).
// m97 structure: global_load_lds(16B) staging, 8 ds_read_b128 : 16 MFMA per k-step.
__global__ __launch_bounds__(256) void dist_mfma(
    const unsigned short* __restrict__ xhi, const unsigned short* __restrict__ xlo,
    const unsigned short* __restrict__ whi, const unsigned short* __restrict__ wlo,
    const float* __restrict__ wn,
    unsigned long long* __restrict__ k1buf, unsigned long long* __restrict__ k2buf)
{
  __shared__ short sA[128 * 32];
  __shared__ short sB[128 * 32];
  const int tid = threadIdx.x;
  const int wv = tid >> 6, lane = tid & 63;
  const int tb = blockIdx.x >> 3, kb = blockIdx.x & 7;
  const int row0 = tb * 128, col0 = kb * 128;
  const int rw = wv & 1, cw = wv >> 1;   // wave covers rows rw*64.., cols cw*64..
  const int q = lane >> 4, cl = lane & 15;

  f32x4 acc[4][4];
  #pragma unroll
  for (int mt = 0; mt < 4; mt++)
    #pragma unroll
    for (int nt = 0; nt < 4; nt++) acc[mt][nt] = (f32x4){0.f, 0.f, 0.f, 0.f};

  const unsigned short* aseg[3] = {xhi, xlo, xhi};
  const unsigned short* bseg[3] = {whi, whi, wlo};

  // staging chunk ids (16B chunks, 4 per 64B row)
  const int cA0 = wv * 64 + lane;          // LDS base wv*1024
  const int cA1 = cA0 + 256;               // LDS base (wv+4)*1024

  for (int ks = 0; ks < 48; ks++) {
    const int seg = ks >> 4;
    const int k0 = (ks & 15) * 32;
    const char* ap = (const char*)aseg[seg];
    const char* bp = (const char*)bseg[seg];
    __syncthreads();
    {
      int r0 = cA0 >> 2, s0 = cA0 & 3;
      int r1 = cA1 >> 2, s1 = cA1 & 3;
      stage16(ap + (size_t)(row0 + r0) * 1024 + k0 * 2 + s0 * 16, (char*)sA + wv * 1024, lane);
      stage16(ap + (size_t)(row0 + r1) * 1024 + k0 * 2 + s1 * 16, (char*)sA + (wv + 4) * 1024, lane);
      stage16(bp + (size_t)(col0 + r0) * 1024 + k0 * 2 + s0 * 16, (char*)sB + wv * 1024, lane);
      stage16(bp + (size_t)(col0 + r1) * 1024 + k0 * 2 + s1 * 16, (char*)sB + (wv + 4) * 1024, lane);
    }
    __syncthreads();
    short8v a[4], b[4];
    #pragma unroll
    for (int mt = 0; mt < 4; mt++) {
      int rl = rw * 64 + mt * 16 + cl;
      a[mt] = *(const short8v*)(sA + rl * 32 + q * 8);
    }
    #pragma unroll
    for (int nt = 0; nt < 4; nt++) {
      int rl = cw * 64 + nt * 16 + cl;
      b[nt] = *(const short8v*)(sB + rl * 32 + q * 8);
    }
    #pragma unroll
    for (int mt = 0; mt < 4; mt++)
      #pragma unroll
      for (int nt = 0; nt < 4; nt++)
        acc[mt][nt] = __builtin_amdgcn_mfma_f32_16x16x32_bf16(a[mt], b[nt], acc[mt][nt], 0, 0, 0);
  }

  // epilogue: dist = wn[k] - 2*dot ; top-2 per token row
  float wnv[4];
  #pragma unroll
  for (int nt = 0; nt < 4; nt++) wnv[nt] = wn[col0 + cw * 64 + nt * 16 + cl];

  const int strip = kb * 2 + cw;
  #pragma unroll
  for (int mt = 0; mt < 4; mt++) {
    #pragma unroll
    for (int r = 0; r < 4; r++) {
      unsigned long long k1 = ~0ull, k2 = ~0ull;
      #pragma unroll
      for (int nt = 0; nt < 4; nt++) {
        int kk = col0 + cw * 64 + nt * 16 + cl;
        float dist = fmaf(-2.f, acc[mt][nt][r], wnv[nt]);
        unsigned long long key = (kk == 0) ? ~0ull
            : ((unsigned long long)ordf(dist) << 32) | (unsigned)kk;
        if (key < k1) { k2 = k1; k1 = key; }
        else if (key < k2) k2 = key;
      }
      #pragma unroll
      for (int off = 8; off > 0; off >>= 1) {
        unsigned long long o1 = __shfl_down(k1, off, 16);
        unsigned long long o2 = __shfl_down(k2, off, 16);
        top2m(k1, k2, o1, o2);
      }
      if (cl == 0) {
        int rowg = row0 + rw * 64 + mt * 16 + q * 4 + r;
        k1buf[strip * N_TOK + rowg] = k1;
        k2buf[strip * N_TOK + rowg] = k2;
      }
    }
  }
}

// ---------------- merge 16 strips, pad mask, margin flag ----------------
__global__ __launch_bounds__(256) void combine_kernel(
    const unsigned long long* __restrict__ k1buf, const unsigned long long* __restrict__ k2buf,
    const int* __restrict__ mask,
    int* __restrict__ idx_i, int* __restrict__ flagList, int* __restrict__ flagcnt)
{
  int t = blockIdx.x * 256 + threadIdx.x;
  unsigned long long a1 = ~0ull, a2 = ~0ull;
  #pragma unroll
  for (int s = 0; s < 16; s++)
    top2m(a1, a2, k1buf[s * N_TOK + t], k2buf[s * N_TOK + t]);
  int bi = (int)(a1 & 0xffffffffu);
  float d1 = ord2f((unsigned)(a1 >> 32));
  float d2 = ord2f((unsigned)(a2 >> 32));
  int pad = mask[t];
  idx_i[t] = pad ? 0 : bi;
  if (!pad && (d2 - d1) < MARGIN) {
    int p = atomicAdd(flagcnt, 1);
    flagList[p] = t;
  }
}

// ---------------- numpy-f32-emulating re-check for near-tie tokens ----------------
__global__ __launch_bounds__(256) void refine_kernel(
    const float* __restrict__ x, const float* __restrict__ w,
    const float* __restrict__ wn32,
    const int* __restrict__ flagList, const int* __restrict__ flagcnt,
    int* __restrict__ idx_i)
{
  __shared__ double xd[DDIM];
  __shared__ double redbuf[4];
  __shared__ float A32sh;
  __shared__ float bv_s[256];
  __shared__ int   bi_s[256];
  int tid = threadIdx.x;
  int lane = tid & 63, wid = tid >> 6;
  int nf = *flagcnt;
  for (int fi = blockIdx.x; fi < nf; fi += gridDim.x) {
    int token = flagList[fi];
    double part = 0.0;
    for (int e = tid; e < DDIM; e += 256) {
      double v = (double)x[(size_t)token * DDIM + e];
      xd[e] = v;
      part += v * v;
    }
    for (int o = 32; o > 0; o >>= 1) part += __shfl_down(part, o, 64);
    if (lane == 0) redbuf[wid] = part;
    __syncthreads();
    if (tid == 0) {
      double a64 = redbuf[0] + redbuf[1] + redbuf[2] + redbuf[3];
      A32sh = (float)a64;
    }
    __syncthreads();
    float A32 = A32sh;
    float bv = 3.4e38f; int bi = 0x7fffffff;
    for (int k = tid; k < KCODE; k += 256) {
      if (k == 0) continue;
      const float4* wr = (const float4*)(w + (size_t)k * DDIM);
      double dot = 0.0;
      #pragma unroll 4
      for (int dq = 0; dq < DDIM / 4; dq++) {
        float4 wv = wr[dq];
        dot += xd[dq*4+0]*(double)wv.x + xd[dq*4+1]*(double)wv.y
             + xd[dq*4+2]*(double)wv.z + xd[dq*4+3]*(double)wv.w;
      }
      float M = (float)dot;
      float AB = A32 + wn32[k];
      float dist = AB - 2.0f * M;
      if (dist < bv) { bv = dist; bi = k; }
    }
    bv_s[tid] = bv; bi_s[tid] = bi;
    __syncthreads();
    for (int st = 128; st > 0; st >>= 1) {
      if (tid < st) {
        if (bv_s[tid+st] < bv_s[tid] ||
            (bv_s[tid+st] == bv_s[tid] && bi_s[tid+st] < bi_s[tid])) {
          bv_s[tid] = bv_s[tid+st]; bi_s[tid] = bi_s[tid+st];
        }
      }
      __syncthreads();
    }
    if (tid == 0) idx_i[token] = bi_s[0];
    __syncthreads();
  }
}

// ---------------- histogram (post-refine) + out_idx ----------------
__global__ __launch_bounds__(256) void hist_kernel(
    const int* __restrict__ idx_i, int* __restrict__ counts_i,
    float* __restrict__ out_idx)
{
  int t = blockIdx.x * 256 + threadIdx.x;
  int id = idx_i[t];
  atomicAdd(&counts_i[id], 1);
  out_idx[t] = (float)id;
}

// ---------------- exclusive scan of counts ----------------
__global__ __launch_bounds__(1024) void scan_kernel(
    const int* __restrict__ counts_i, int* __restrict__ offsets, int* __restrict__ cursor)
{
  __shared__ int tmp[1024];
  int t = threadIdx.x;
  int c = counts_i[t];
  tmp[t] = c;
  __syncthreads();
  for (int off = 1; off < 1024; off <<= 1) {
    int v = (t >= off) ? tmp[t - off] : 0;
    __syncthreads();
    tmp[t] += v;
    __syncthreads();
  }
  int ex = tmp[t] - c;
  offsets[t] = ex;
  cursor[t] = ex;
}

// ---------------- scatter tokens into per-code buckets ----------------
__global__ __launch_bounds__(256) void scatter_kernel(
    const int* __restrict__ idx_i, int* __restrict__ cursor, int* __restrict__ bucket)
{
  int t = blockIdx.x * 256 + threadIdx.x;
  int id = idx_i[t];
  int p = atomicAdd(&cursor[id], 1);
  bucket[p] = t;
}

// ---------------- quantized output + loss (16 tokens/block) ----------------
__global__ __launch_bounds__(256) void quant_kernel(
    const float* __restrict__ x, const float* __restrict__ w,
    const int* __restrict__ idx_i,
    float* __restrict__ out_q, float* __restrict__ losssum)
{
  __shared__ float sred[4];
  int tid = threadIdx.x;
  int qd = tid & 127, h = tid >> 7;
  float s = 0.f;
  #pragma unroll
  for (int i = 0; i < 8; i++) {
    int token = blockIdx.x * 16 + i * 2 + h;
    int idx = idx_i[token];
    float4 xv = *(const float4*)(x + (size_t)token * DDIM + qd * 4);
    float4 wv = *(const float4*)(w + (size_t)idx * DDIM + qd * 4);
    *(float4*)(out_q + (size_t)token * DDIM + qd * 4) = wv;
    float dx = wv.x - xv.x, dy = wv.y - xv.y, dz = wv.z - xv.z, dww = wv.w - xv.w;
    s += dx*dx + dy*dy + dz*dz + dww*dww;
  }
  for (int o = 32; o > 0; o >>= 1) s += __shfl_down(s, o, 64);
  int lane = tid & 63, wid = tid >> 6;
  if (lane == 0) sred[wid] = s;
  __syncthreads();
  if (tid == 0) atomicAdd(losssum, sred[0] + sred[1] + sred[2] + sred[3]);
}

// ---------------- dw: per (code, slice) register accumulation ----------------
__global__ __launch_bounds__(128) void dw_kernel(
    const float* __restrict__ x, const int* __restrict__ bucket,
    const int* __restrict__ offsets, const int* __restrict__ counts_i,
    float* __restrict__ dwpart, int S)
{
  int s = blockIdx.x;
  int code = blockIdx.y;
  int t = threadIdx.x;
  float4 acc0 = make_float4(0.f, 0.f, 0.f, 0.f);
  float4 acc1 = make_float4(0.f, 0.f, 0.f, 0.f);
  int base = offsets[code], cnt = counts_i[code];
  int j = s;
  for (; j + S < cnt; j += 2 * S) {   // 2-way unroll: independent loads in flight
    int tk0 = bucket[base + j];
    int tk1 = bucket[base + j + S];
    float4 v0 = *(const float4*)(x + (size_t)tk0 * DDIM + t * 4);
    float4 v1 = *(const float4*)(x + (size_t)tk1 * DDIM + t * 4);
    acc0.x += v0.x; acc0.y += v0.y; acc0.z += v0.z; acc0.w += v0.w;
    acc1.x += v1.x; acc1.y += v1.y; acc1.z += v1.z; acc1.w += v1.w;
  }
  if (j < cnt) {
    int tk0 = bucket[base + j];
    float4 v0 = *(const float4*)(x + (size_t)tk0 * DDIM + t * 4);
    acc0.x += v0.x; acc0.y += v0.y; acc0.z += v0.z; acc0.w += v0.w;
  }
  acc0.x += acc1.x; acc0.y += acc1.y; acc0.z += acc1.z; acc0.w += acc1.w;
  *(float4*)(dwpart + ((size_t)s * KCODE + code) * DDIM + t * 4) = acc0;
}

// ---------------- cs / loss / perplexity ----------------
__global__ __launch_bounds__(1024) void stats_kernel(
    const int* __restrict__ counts_i, const float* __restrict__ ema_cs,
    const float* __restrict__ losssum,
    float* __restrict__ out_loss, float* __restrict__ out_perp,
    float* __restrict__ out_cs)
{
  __shared__ float sbuf[17];
  int k = threadIdx.x;
  float cnt = (float)counts_i[k];
  float csr = ema_cs[k] * DECAYF + (1.f - DECAYF) * cnt;
  float v = csr;
  for (int o = 32; o > 0; o >>= 1) v += __shfl_down(v, o, 64);
  int lane = k & 63, wid = k >> 6;
  if (lane == 0) sbuf[wid] = v;
  __syncthreads();
  if (k == 0) { float n = 0.f; for (int i = 0; i < 16; i++) n += sbuf[i]; sbuf[16] = n; }
  __syncthreads();
  float n = sbuf[16];
  out_cs[k] = (csr + EPSV) / (n + (float)KCODE * EPSV) * n;
  __syncthreads();
  float p = cnt / (float)N_TOK;
  v = p * logf(p + 1e-10f);
  for (int o = 32; o > 0; o >>= 1) v += __shfl_down(v, o, 64);
  if (lane == 0) sbuf[wid] = v;
  __syncthreads();
  if (k == 0) {
    float s = 0.f; for (int i = 0; i < 16; i++) s += sbuf[i];
    out_perp[0] = expf(-s);
    float nonpad = (float)(N_TOK - counts_i[0]);
    out_loss[0] = CCOST * losssum[0] / (nonpad * (float)DDIM);
  }
}

// ---------------- EMA update + new codebook ----------------
__global__ __launch_bounds__(256) void ema_kernel(
    const float* __restrict__ ema_w, const float* __restrict__ dwpart,
    const float* __restrict__ cs, int S,
    float* __restrict__ out_ema, float* __restrict__ out_cb)
{
  int i = blockIdx.x * 256 + threadIdx.x;
  int e = i * 4;
  int k = e >> 9;
  float4 dv = make_float4(0.f, 0.f, 0.f, 0.f);
  for (int s = 0; s < S; s++) {
    float4 p = *(const float4*)(dwpart + (size_t)s * KCODE * DDIM + e);
    dv.x += p.x; dv.y += p.y; dv.z += p.z; dv.w += p.w;
  }
  float4 ew = *(const float4*)(ema_w + e);
  float4 ne;
  ne.x = ew.x * DECAYF + (1.f - DECAYF) * dv.x;
  ne.y = ew.y * DECAYF + (1.f - DECAYF) * dv.y;
  ne.z = ew.z * DECAYF + (1.f - DECAYF) * dv.z;
  ne.w = ew.w * DECAYF + (1.f - DECAYF) * dv.w;
  *(float4*)(out_ema + e) = ne;
  float4 cb;
  if (k == 0) { cb.x = 0.f; cb.y = 0.f; cb.z = 0.f; cb.w = 0.f; }
  else {
    float csk = cs[k];
    cb.x = ne.x / csk; cb.y = ne.y / csk; cb.z = ne.z / csk; cb.w = ne.w / csk;
  }
  *(float4*)(out_cb + e) = cb;
}

extern "C" void kernel_launch(void* const* d_in, const int* in_sizes, int n_in,
                              void* d_out, int out_size, void* d_ws, size_t ws_size,
                              hipStream_t stream) {
  const float* x      = (const float*)d_in[0];
  const int*   mask   = (const int*)d_in[1];
  const float* w      = (const float*)d_in[2];
  const float* ema_cs = (const float*)d_in[3];
  const float* ema_w  = (const float*)d_in[4];
  float* out = (float*)d_out;

  float* out_q    = out;                  // 16777216  quantized_st
  float* out_idx  = out + 16777216;       // 32768     idx (as float)
  float* out_loss = out + 16809984;       // 1
  float* out_perp = out + 16809985;       // 1
  float* out_cs   = out + 16809986;       // 1024
  float* out_ema  = out + 16811010;       // 524288
  float* out_cb   = out + 17335298;       // 524288

  // xhi/xlo live in the (dead until quant) out_q region: 2 x 32 MB = 64 MB
  unsigned short* xhi = (unsigned short*)out_q;
  unsigned short* xlo = xhi + (size_t)N_TOK * DDIM;

  char* ws = (char*)d_ws;
  int*   counts_i = (int*)  (ws + 0);          // 4 KB (zeroed)
  float* losssum  = (float*)(ws + 4096);       // 4 B  (zeroed)
  int*   flagcnt  = (int*)  (ws + 4100);       // 4 B  (zeroed)
  int*   offsets  = (int*)  (ws + 8192);       // 4 KB
  int*   cursor   = (int*)  (ws + 12288);      // 4 KB
  float* wn       = (float*)(ws + 16384);      // 4 KB
  int*   idx_i    = (int*)  (ws + 20480);      // 128 KB
  int*   bucket   = (int*)  (ws + 151552);     // 128 KB
  unsigned short* whi = (unsigned short*)(ws + 282624);   // 1 MB
  unsigned short* wlo = (unsigned short*)(ws + 1331200);  // 1 MB
  unsigned long long* k1buf = (unsigned long long*)(ws + 2379776);  // 4 MB
  unsigned long long* k2buf = (unsigned long long*)(ws + 6574080);  // 4 MB
  int*   flagList = (int*)  (ws + 10768384);   // 128 KB
  float* dwpart   = (float*)(ws + 10899456);   // S * 2 MB

  size_t dwbase = 10899456ull;
  int S = 1;
  if      (ws_size >= dwbase + 8ull * 2097152ull) S = 8;
  else if (ws_size >= dwbase + 4ull * 2097152ull) S = 4;
  else if (ws_size >= dwbase + 2ull * 2097152ull) S = 2;

  hipMemsetAsync(ws, 0, 4104, stream);
  convert_x<<<(N_TOK * DDIM / 4) / 256, 256, 0, stream>>>(x, xhi, xlo);
  convert_w<<<KCODE, 64, 0, stream>>>(w, whi, wlo, wn);
  dist_mfma<<<(N_TOK / 128) * 8, 256, 0, stream>>>(xhi, xlo, whi, wlo, wn, k1buf, k2buf);
  combine_kernel<<<N_TOK / 256, 256, 0, stream>>>(k1buf, k2buf, mask, idx_i, flagList, flagcnt);
  refine_kernel<<<1024, 256, 0, stream>>>(x, w, wn, flagList, flagcnt, idx_i);
  hist_kernel<<<N_TOK / 256, 256, 0, stream>>>(idx_i, counts_i, out_idx);
  scan_kernel<<<1, 1024, 0, stream>>>(counts_i, offsets, cursor);
  scatter_kernel<<<N_TOK / 256, 256, 0, stream>>>(idx_i, cursor, bucket);
  quant_kernel<<<N_TOK / 16, 256, 0, stream>>>(x, w, idx_i, out_q, losssum);
  dw_kernel<<<dim3(S, KCODE), 128, 0, stream>>>(x, bucket, offsets, counts_i, dwpart, S);
  stats_kernel<<<1, 1024, 0, stream>>>(counts_i, ema_cs, losssum, out_loss, out_perp, out_cs);
  ema_kernel<<<KCODE * DDIM / 4 / 256, 256, 0, stream>>>(ema_w, dwpart, out_cs, S, out_ema, out_cb);
}

// Round 5
// 480.088 us; speedup vs baseline: 2.6148x; 1.5108x over previous
//
#include <hip/hip_runtime.h>
#include <math.h>

#define N_TOK 32768
#define DDIM  512
#define KCODE 1024
#define DECAYF 0.99f
#define EPSV 1e-5f
#define CCOST 0.25f
#define MARGIN 1e-3f

typedef float f32x4 __attribute__((ext_vector_type(4)));
typedef short short8v __attribute__((ext_vector_type(8)));

// ---- bf16 helpers (RTN-even) ----
__device__ __forceinline__ unsigned short f2bf(float f) {
  unsigned u = __float_as_uint(f);
  u += 0x7fffu + ((u >> 16) & 1u);
  return (unsigned short)(u >> 16);
}
__device__ __forceinline__ float bf2f(unsigned short h) {
  return __uint_as_float(((unsigned)h) << 16);
}

// ---- monotone float<->ordered-uint for argmin key packing ----
__device__ __forceinline__ unsigned ordf(float f) {
  unsigned u = __float_as_uint(f);
  return (u & 0x80000000u) ? ~u : (u | 0x80000000u);
}
__device__ __forceinline__ float ord2f(unsigned v) {
  unsigned u = (v & 0x80000000u) ? (v & 0x7fffffffu) : ~v;
  return __uint_as_float(u);
}
__device__ __forceinline__ void top2m(unsigned long long& a1, unsigned long long& a2,
                                      unsigned long long b1, unsigned long long b2) {
  unsigned long long m1 = a1 < b1 ? a1 : b1;
  unsigned long long hi = a1 < b1 ? b1 : a1;
  unsigned long long m2 = a2 < b2 ? a2 : b2;
  a2 = m2 < hi ? m2 : hi;
  a1 = m1;
}

// ---- async global->LDS, 16B/lane ----
__device__ __forceinline__ void stage16(const void* g, char* lds_base, int lane) {
#if __has_builtin(__builtin_amdgcn_global_load_lds)
  __builtin_amdgcn_global_load_lds((const __attribute__((address_space(1))) void*)g,
                                   (__attribute__((address_space(3))) void*)lds_base,
                                   16, 0, 0);
#else
  *(float4*)(lds_base + lane * 16) = *(const float4*)g;
#endif
}

// ---------------- fused conversion: x and w -> bf16 hi/lo, + w fp64 norms ----------------
__global__ __launch_bounds__(256) void convert_fused(
    const float* __restrict__ x, const float* __restrict__ w,
    unsigned short* __restrict__ xhi, unsigned short* __restrict__ xlo,
    unsigned short* __restrict__ whi, unsigned short* __restrict__ wlo,
    float* __restrict__ wn)
{
  int b = blockIdx.x;
  int tid = threadIdx.x;
  if (b < 16384) {              // x part: 16384 blocks x 256 thr x float4
    size_t i = (size_t)b * 256 + tid;
    float4 v = *(const float4*)(x + i * 4);
    ushort4 h, l;
    h.x = f2bf(v.x); l.x = f2bf(v.x - bf2f(h.x));
    h.y = f2bf(v.y); l.y = f2bf(v.y - bf2f(h.y));
    h.z = f2bf(v.z); l.z = f2bf(v.z - bf2f(h.z));
    h.w = f2bf(v.w); l.w = f2bf(v.w - bf2f(h.w));
    *(ushort4*)(xhi + i * 4) = h;
    *(ushort4*)(xlo + i * 4) = l;
  } else {                      // w part: 256 blocks, each wave handles one row
    int k = (b - 16384) * 4 + (tid >> 6);
    int lane = tid & 63;
    double s = 0.0;
    #pragma unroll
    for (int it = 0; it < 2; it++) {
      size_t off = (size_t)k * DDIM + (lane + 64 * it) * 4;
      float4 v = *(const float4*)(w + off);
      s += (double)v.x*(double)v.x + (double)v.y*(double)v.y
         + (double)v.z*(double)v.z + (double)v.w*(double)v.w;
      ushort4 h, l;
      h.x = f2bf(v.x); l.x = f2bf(v.x - bf2f(h.x));
      h.y = f2bf(v.y); l.y = f2bf(v.y - bf2f(h.y));
      h.z = f2bf(v.z); l.z = f2bf(v.z - bf2f(h.z));
      h.w = f2bf(v.w); l.w = f2bf(v.w - bf2f(h.w));
      *(ushort4*)(whi + off) = h;
      *(ushort4*)(wlo + off) = l;
    }
    for (int o = 32; o > 0; o >>= 1) s += __shfl_down(s, o, 64);
    if (lane == 0) wn[k] = (float)s;
  }
}

// ---------------- MFMA distance + top-2 argmin (unchanged from R4) ----------------
__global__ __launch_bounds__(256) void dist_mfma(
    const unsigned short* __restrict__ xhi, const unsigned short* __restrict__ xlo,
    const unsigned short* __restrict__ whi, const unsigned short* __restrict__ wlo,
    const float* __restrict__ wn,
    unsigned long long* __restrict__ k1buf, unsigned long long* __restrict__ k2buf)
{
  __shared__ short sA[128 * 32];
  __shared__ short sB[128 * 32];
  const int tid = threadIdx.x;
  const int wv = tid >> 6, lane = tid & 63;
  const int tb = blockIdx.x >> 3, kb = blockIdx.x & 7;
  const int row0 = tb * 128, col0 = kb * 128;
  const int rw = wv & 1, cw = wv >> 1;
  const int q = lane >> 4, cl = lane & 15;

  f32x4 acc[4][4];
  #pragma unroll
  for (int mt = 0; mt < 4; mt++)
    #pragma unroll
    for (int nt = 0; nt < 4; nt++) acc[mt][nt] = (f32x4){0.f, 0.f, 0.f, 0.f};

  const unsigned short* aseg[3] = {xhi, xlo, xhi};
  const unsigned short* bseg[3] = {whi, whi, wlo};

  const int cA0 = wv * 64 + lane;
  const int cA1 = cA0 + 256;

  for (int ks = 0; ks < 48; ks++) {
    const int seg = ks >> 4;
    const int k0 = (ks & 15) * 32;
    const char* ap = (const char*)aseg[seg];
    const char* bp = (const char*)bseg[seg];
    __syncthreads();
    {
      int r0 = cA0 >> 2, s0 = cA0 & 3;
      int r1 = cA1 >> 2, s1 = cA1 & 3;
      stage16(ap + (size_t)(row0 + r0) * 1024 + k0 * 2 + s0 * 16, (char*)sA + wv * 1024, lane);
      stage16(ap + (size_t)(row0 + r1) * 1024 + k0 * 2 + s1 * 16, (char*)sA + (wv + 4) * 1024, lane);
      stage16(bp + (size_t)(col0 + r0) * 1024 + k0 * 2 + s0 * 16, (char*)sB + wv * 1024, lane);
      stage16(bp + (size_t)(col0 + r1) * 1024 + k0 * 2 + s1 * 16, (char*)sB + (wv + 4) * 1024, lane);
    }
    __syncthreads();
    short8v a[4], b[4];
    #pragma unroll
    for (int mt = 0; mt < 4; mt++) {
      int rl = rw * 64 + mt * 16 + cl;
      a[mt] = *(const short8v*)(sA + rl * 32 + q * 8);
    }
    #pragma unroll
    for (int nt = 0; nt < 4; nt++) {
      int rl = cw * 64 + nt * 16 + cl;
      b[nt] = *(const short8v*)(sB + rl * 32 + q * 8);
    }
    #pragma unroll
    for (int mt = 0; mt < 4; mt++)
      #pragma unroll
      for (int nt = 0; nt < 4; nt++)
        acc[mt][nt] = __builtin_amdgcn_mfma_f32_16x16x32_bf16(a[mt], b[nt], acc[mt][nt], 0, 0, 0);
  }

  float wnv[4];
  #pragma unroll
  for (int nt = 0; nt < 4; nt++) wnv[nt] = wn[col0 + cw * 64 + nt * 16 + cl];

  const int strip = kb * 2 + cw;
  #pragma unroll
  for (int mt = 0; mt < 4; mt++) {
    #pragma unroll
    for (int r = 0; r < 4; r++) {
      unsigned long long k1 = ~0ull, k2 = ~0ull;
      #pragma unroll
      for (int nt = 0; nt < 4; nt++) {
        int kk = col0 + cw * 64 + nt * 16 + cl;
        float dist = fmaf(-2.f, acc[mt][nt][r], wnv[nt]);
        unsigned long long key = (kk == 0) ? ~0ull
            : ((unsigned long long)ordf(dist) << 32) | (unsigned)kk;
        if (key < k1) { k2 = k1; k1 = key; }
        else if (key < k2) k2 = key;
      }
      #pragma unroll
      for (int off = 8; off > 0; off >>= 1) {
        unsigned long long o1 = __shfl_down(k1, off, 16);
        unsigned long long o2 = __shfl_down(k2, off, 16);
        top2m(k1, k2, o1, o2);
      }
      if (cl == 0) {
        int rowg = row0 + rw * 64 + mt * 16 + q * 4 + r;
        k1buf[strip * N_TOK + rowg] = k1;
        k2buf[strip * N_TOK + rowg] = k2;
      }
    }
  }
}

// ---------------- merge strips + pad mask + margin flag + LDS histogram ----------------
__global__ __launch_bounds__(1024) void combine_kernel(
    const unsigned long long* __restrict__ k1buf, const unsigned long long* __restrict__ k2buf,
    const int* __restrict__ mask,
    int* __restrict__ idx_i, int* __restrict__ flagList, int* __restrict__ flagcnt,
    int* __restrict__ counts_i)
{
  __shared__ int lh[KCODE];
  int tid = threadIdx.x;
  lh[tid] = 0;
  __syncthreads();
  int t = blockIdx.x * 1024 + tid;
  unsigned long long a1 = ~0ull, a2 = ~0ull;
  #pragma unroll
  for (int s = 0; s < 16; s++)
    top2m(a1, a2, k1buf[s * N_TOK + t], k2buf[s * N_TOK + t]);
  int bi = (int)(a1 & 0xffffffffu);
  float d1 = ord2f((unsigned)(a1 >> 32));
  float d2 = ord2f((unsigned)(a2 >> 32));
  int pad = mask[t];
  int id = pad ? 0 : bi;
  idx_i[t] = id;
  atomicAdd(&lh[id], 1);
  if (!pad && (d2 - d1) < MARGIN) {
    int p = atomicAdd(flagcnt, 1);
    flagList[p] = t;
  }
  __syncthreads();
  if (lh[tid] > 0) atomicAdd(&counts_i[tid], lh[tid]);
}

// ---------------- numpy-f32-emulating re-check + counts patch ----------------
__global__ __launch_bounds__(256) void refine_kernel(
    const float* __restrict__ x, const float* __restrict__ w,
    const float* __restrict__ wn32,
    const int* __restrict__ flagList, const int* __restrict__ flagcnt,
    int* __restrict__ idx_i, int* __restrict__ counts_i)
{
  __shared__ double xd[DDIM];
  __shared__ double redbuf[4];
  __shared__ float A32sh;
  __shared__ float bv_s[256];
  __shared__ int   bi_s[256];
  int tid = threadIdx.x;
  int lane = tid & 63, wid = tid >> 6;
  int nf = *flagcnt;
  for (int fi = blockIdx.x; fi < nf; fi += gridDim.x) {
    int token = flagList[fi];
    double part = 0.0;
    for (int e = tid; e < DDIM; e += 256) {
      double v = (double)x[(size_t)token * DDIM + e];
      xd[e] = v;
      part += v * v;
    }
    for (int o = 32; o > 0; o >>= 1) part += __shfl_down(part, o, 64);
    if (lane == 0) redbuf[wid] = part;
    __syncthreads();
    if (tid == 0) {
      double a64 = redbuf[0] + redbuf[1] + redbuf[2] + redbuf[3];
      A32sh = (float)a64;
    }
    __syncthreads();
    float A32 = A32sh;
    float bv = 3.4e38f; int bi = 0x7fffffff;
    for (int k = tid; k < KCODE; k += 256) {
      if (k == 0) continue;
      const float4* wr = (const float4*)(w + (size_t)k * DDIM);
      double dot = 0.0;
      #pragma unroll 4
      for (int dq = 0; dq < DDIM / 4; dq++) {
        float4 wv = wr[dq];
        dot += xd[dq*4+0]*(double)wv.x + xd[dq*4+1]*(double)wv.y
             + xd[dq*4+2]*(double)wv.z + xd[dq*4+3]*(double)wv.w;
      }
      float M = (float)dot;
      float AB = A32 + wn32[k];
      float dist = AB - 2.0f * M;
      if (dist < bv) { bv = dist; bi = k; }
    }
    bv_s[tid] = bv; bi_s[tid] = bi;
    __syncthreads();
    for (int st = 128; st > 0; st >>= 1) {
      if (tid < st) {
        if (bv_s[tid+st] < bv_s[tid] ||
            (bv_s[tid+st] == bv_s[tid] && bi_s[tid+st] < bi_s[tid])) {
          bv_s[tid] = bv_s[tid+st]; bi_s[tid] = bi_s[tid+st];
        }
      }
      __syncthreads();
    }
    if (tid == 0) {
      int old = idx_i[token];
      int nw = bi_s[0];
      if (nw != old) {
        idx_i[token] = nw;
        atomicSub(&counts_i[old], 1);
        atomicAdd(&counts_i[nw], 1);
      }
    }
    __syncthreads();
  }
}

// ---------------- exclusive scan of counts ----------------
__global__ __launch_bounds__(1024) void scan_kernel(
    const int* __restrict__ counts_i, int* __restrict__ offsets, int* __restrict__ cursor)
{
  __shared__ int tmp[1024];
  int t = threadIdx.x;
  int c = counts_i[t];
  tmp[t] = c;
  __syncthreads();
  for (int off = 1; off < 1024; off <<= 1) {
    int v = (t >= off) ? tmp[t - off] : 0;
    __syncthreads();
    tmp[t] += v;
    __syncthreads();
  }
  int ex = tmp[t] - c;
  offsets[t] = ex;
  cursor[t] = ex;
}

// ---------------- scatter with LDS rank aggregation ----------------
__global__ __launch_bounds__(1024) void scatter_kernel(
    const int* __restrict__ idx_i, int* __restrict__ cursor, int* __restrict__ bucket)
{
  __shared__ int lh[KCODE];
  __shared__ int lb[KCODE];
  int tid = threadIdx.x;
  lh[tid] = 0;
  __syncthreads();
  int token = blockIdx.x * 1024 + tid;
  int id = idx_i[token];
  int r = atomicAdd(&lh[id], 1);
  __syncthreads();
  if (lh[tid] > 0) lb[tid] = atomicAdd(&cursor[tid], lh[tid]);
  __syncthreads();
  bucket[lb[id] + r] = token;
}

// ---------------- quantized output + out_idx + loss ----------------
__global__ __launch_bounds__(256) void quant_kernel(
    const float* __restrict__ x, const float* __restrict__ w,
    const int* __restrict__ idx_i,
    float* __restrict__ out_q, float* __restrict__ out_idx, float* __restrict__ losssum)
{
  __shared__ float sred[4];
  int tid = threadIdx.x;
  int qd = tid & 127, h = tid >> 7;
  float s = 0.f;
  #pragma unroll
  for (int i = 0; i < 8; i++) {
    int token = blockIdx.x * 16 + i * 2 + h;
    int idx = idx_i[token];
    float4 xv = *(const float4*)(x + (size_t)token * DDIM + qd * 4);
    float4 wv = *(const float4*)(w + (size_t)idx * DDIM + qd * 4);
    *(float4*)(out_q + (size_t)token * DDIM + qd * 4) = wv;
    if (qd == 0) out_idx[token] = (float)idx;
    float dx = wv.x - xv.x, dy = wv.y - xv.y, dz = wv.z - xv.z, dww = wv.w - xv.w;
    s += dx*dx + dy*dy + dz*dz + dww*dww;
  }
  for (int o = 32; o > 0; o >>= 1) s += __shfl_down(s, o, 64);
  int lane = tid & 63, wid = tid >> 6;
  if (lane == 0) sred[wid] = s;
  __syncthreads();
  if (tid == 0) atomicAdd(losssum, sred[0] + sred[1] + sred[2] + sred[3]);
}

// ---------------- dw: balanced contiguous bucket ranges, run-flush atomics ----------------
__global__ __launch_bounds__(128) void dw_kernel(
    const float* __restrict__ x, const int* __restrict__ bucket,
    const int* __restrict__ idx_i, float* __restrict__ dw)
{
  int b0 = blockIdx.x * 32;
  int t = threadIdx.x;
  // per-lane: entry (t&31); broadcast via shuffle in the loop
  int ent = bucket[b0 + (t & 31)];
  int eid = idx_i[ent];
  int tok0 = __shfl(ent, 0, 64);
  int cur  = __shfl(eid, 0, 64);
  float4 acc = make_float4(0.f, 0.f, 0.f, 0.f);
  float4 nv = *(const float4*)(x + (size_t)tok0 * DDIM + t * 4);
  for (int j = 0; j < 32; j++) {
    float4 v = nv;
    int id = __shfl(eid, j, 64);
    if (j < 31) {
      int tn = __shfl(ent, j + 1, 64);
      nv = *(const float4*)(x + (size_t)tn * DDIM + t * 4);
    }
    if (id != cur) {   // wave-uniform branch
      float* p = dw + (size_t)cur * DDIM + t * 4;
      atomicAdd(p + 0, acc.x); atomicAdd(p + 1, acc.y);
      atomicAdd(p + 2, acc.z); atomicAdd(p + 3, acc.w);
      acc = make_float4(0.f, 0.f, 0.f, 0.f);
      cur = id;
    }
    acc.x += v.x; acc.y += v.y; acc.z += v.z; acc.w += v.w;
  }
  float* p = dw + (size_t)cur * DDIM + t * 4;
  atomicAdd(p + 0, acc.x); atomicAdd(p + 1, acc.y);
  atomicAdd(p + 2, acc.z); atomicAdd(p + 3, acc.w);
}

// ---------------- cs / loss / perplexity ----------------
__global__ __launch_bounds__(1024) void stats_kernel(
    const int* __restrict__ counts_i, const float* __restrict__ ema_cs,
    const float* __restrict__ losssum,
    float* __restrict__ out_loss, float* __restrict__ out_perp,
    float* __restrict__ out_cs)
{
  __shared__ float sbuf[17];
  int k = threadIdx.x;
  float cnt = (float)counts_i[k];
  float csr = ema_cs[k] * DECAYF + (1.f - DECAYF) * cnt;
  float v = csr;
  for (int o = 32; o > 0; o >>= 1) v += __shfl_down(v, o, 64);
  int lane = k & 63, wid = k >> 6;
  if (lane == 0) sbuf[wid] = v;
  __syncthreads();
  if (k == 0) { float n = 0.f; for (int i = 0; i < 16; i++) n += sbuf[i]; sbuf[16] = n; }
  __syncthreads();
  float n = sbuf[16];
  out_cs[k] = (csr + EPSV) / (n + (float)KCODE * EPSV) * n;
  __syncthreads();
  float p = cnt / (float)N_TOK;
  v = p * logf(p + 1e-10f);
  for (int o = 32; o > 0; o >>= 1) v += __shfl_down(v, o, 64);
  if (lane == 0) sbuf[wid] = v;
  __syncthreads();
  if (k == 0) {
    float s = 0.f; for (int i = 0; i < 16; i++) s += sbuf[i];
    out_perp[0] = expf(-s);
    float nonpad = (float)(N_TOK - counts_i[0]);
    out_loss[0] = CCOST * losssum[0] / (nonpad * (float)DDIM);
  }
}

// ---------------- EMA update + new codebook ----------------
__global__ __launch_bounds__(256) void ema_kernel(
    const float* __restrict__ ema_w, const float* __restrict__ dw,
    const float* __restrict__ cs,
    float* __restrict__ out_ema, float* __restrict__ out_cb)
{
  int i = blockIdx.x * 256 + threadIdx.x;
  int e = i * 4;
  int k = e >> 9;
  float4 dv = *(const float4*)(dw + e);
  float4 ew = *(const float4*)(ema_w + e);
  float4 ne;
  ne.x = ew.x * DECAYF + (1.f - DECAYF) * dv.x;
  ne.y = ew.y * DECAYF + (1.f - DECAYF) * dv.y;
  ne.z = ew.z * DECAYF + (1.f - DECAYF) * dv.z;
  ne.w = ew.w * DECAYF + (1.f - DECAYF) * dv.w;
  *(float4*)(out_ema + e) = ne;
  float4 cb;
  if (k == 0) { cb.x = 0.f; cb.y = 0.f; cb.z = 0.f; cb.w = 0.f; }
  else {
    float csk = cs[k];
    cb.x = ne.x / csk; cb.y = ne.y / csk; cb.z = ne.z / csk; cb.w = ne.w / csk;
  }
  *(float4*)(out_cb + e) = cb;
}

extern "C" void kernel_launch(void* const* d_in, const int* in_sizes, int n_in,
                              void* d_out, int out_size, void* d_ws, size_t ws_size,
                              hipStream_t stream) {
  const float* x      = (const float*)d_in[0];
  const int*   mask   = (const int*)d_in[1];
  const float* w      = (const float*)d_in[2];
  const float* ema_cs = (const float*)d_in[3];
  const float* ema_w  = (const float*)d_in[4];
  float* out = (float*)d_out;

  float* out_q    = out;                  // 16777216  quantized_st
  float* out_idx  = out + 16777216;       // 32768     idx (as float)
  float* out_loss = out + 16809984;       // 1
  float* out_perp = out + 16809985;       // 1
  float* out_cs   = out + 16809986;       // 1024
  float* out_ema  = out + 16811010;       // 524288
  float* out_cb   = out + 17335298;       // 524288

  // xhi/xlo live in the (dead until quant) out_q region: 2 x 32 MB
  unsigned short* xhi = (unsigned short*)out_q;
  unsigned short* xlo = xhi + (size_t)N_TOK * DDIM;

  char* ws = (char*)d_ws;
  int*   counts_i = (int*)  (ws + 0);          // 4 KB   (zeroed)
  float* dw       = (float*)(ws + 4096);       // 2 MB   (zeroed)
  float* losssum  = (float*)(ws + 2101248);    // 4 B    (zeroed)
  int*   flagcnt  = (int*)  (ws + 2101252);    // 4 B    (zeroed)
  int*   offsets  = (int*)  (ws + 2101312);    // 4 KB
  int*   cursor   = (int*)  (ws + 2105408);    // 4 KB
  float* wn       = (float*)(ws + 2109504);    // 4 KB
  int*   idx_i    = (int*)  (ws + 2113600);    // 128 KB
  int*   bucket   = (int*)  (ws + 2244672);    // 128 KB
  unsigned short* whi = (unsigned short*)(ws + 2375744);   // 1 MB
  unsigned short* wlo = (unsigned short*)(ws + 3424320);   // 1 MB
  unsigned long long* k1buf = (unsigned long long*)(ws + 4472896);  // 4 MB
  unsigned long long* k2buf = (unsigned long long*)(ws + 8667200);  // 4 MB
  int*   flagList = (int*)  (ws + 12861504);   // 128 KB -> total ~13 MB

  hipMemsetAsync(ws, 0, 2101256, stream);  // counts + dw + losssum + flagcnt
  convert_fused<<<16384 + 256, 256, 0, stream>>>(x, w, xhi, xlo, whi, wlo, wn);
  dist_mfma<<<(N_TOK / 128) * 8, 256, 0, stream>>>(xhi, xlo, whi, wlo, wn, k1buf, k2buf);
  combine_kernel<<<N_TOK / 1024, 1024, 0, stream>>>(k1buf, k2buf, mask, idx_i, flagList, flagcnt, counts_i);
  refine_kernel<<<1024, 256, 0, stream>>>(x, w, wn, flagList, flagcnt, idx_i, counts_i);
  scan_kernel<<<1, 1024, 0, stream>>>(counts_i, offsets, cursor);
  scatter_kernel<<<N_TOK / 1024, 1024, 0, stream>>>(idx_i, cursor, bucket);
  quant_kernel<<<N_TOK / 16, 256, 0, stream>>>(x, w, idx_i, out_q, out_idx, losssum);
  dw_kernel<<<N_TOK / 32, 128, 0, stream>>>(x, bucket, idx_i, dw);
  stats_kernel<<<1, 1024, 0, stream>>>(counts_i, ema_cs, losssum, out_loss, out_perp, out_cs);
  ema_kernel<<<KCODE * DDIM / 4 / 256, 256, 0, stream>>>(ema_w, dw, out_cs, out_ema, out_cb);
}